// Round 10
// baseline (84.683 us; speedup 1.0000x reference)
//
#include <hip/hip_runtime.h>
#include <stdint.h>

#define A_DIM 8192
#define B_DIM 8192
#define K_CL  256
#define NSLAB 8
#define SLABW (B_DIM / NSLAB)   // 1024
#define NKS   (SLABW / 64)      // 16 K-steps of 64

typedef short bf16x8 __attribute__((ext_vector_type(8)));
typedef float f32x4  __attribute__((ext_vector_type(4)));
typedef float f32x16 __attribute__((ext_vector_type(16)));
typedef unsigned short u16;

__device__ __forceinline__ u16 f2bf(float f) {
    unsigned int u = __float_as_uint(f);
    u += 0x7fffu + ((u >> 16) & 1u);   // RNE (prep only)
    return (u16)(u >> 16);
}

// ---------- prep: pack p_r into 32x32x16 MFMA B-fragment layout, bf16 ----------
// Bpack[((kb2*8 + c2)*64 + lane)*8 + j] = bf16(p_r[kb2*16 + (lane>>5)*8 + j][c2*32 + (lane&31)])
__global__ __launch_bounds__(256) void k_prep(const float* __restrict__ pr,
                                              u16* __restrict__ Bpack,
                                              float* __restrict__ out) {
    const int kb2 = blockIdx.x;          // 0..511
    const int t = threadIdx.x;
    if (kb2 == 0 && t == 0) out[0] = 0.0f;
    const int lane = t & 63, wv = t >> 6;
    const int l31 = lane & 31, half = lane >> 5;
#pragma unroll
    for (int ci = 0; ci < 2; ci++) {
        const int c2 = wv * 2 + ci;
        float v[8];
#pragma unroll
        for (int j = 0; j < 8; j++)
            v[j] = pr[(size_t)(kb2 * 16 + half * 8 + j) * K_CL + c2 * 32 + l31];
        union { bf16x8 b; unsigned int u[4]; } o;
#pragma unroll
        for (int j = 0; j < 4; j++)
            o.u[j] = (unsigned int)f2bf(v[2 * j]) | ((unsigned int)f2bf(v[2 * j + 1]) << 16);
        *(bf16x8*)(Bpack + ((size_t)(kb2 * 8 + c2) * 64 + lane) * 8) = o.b;
    }
}

// ---------- main: [G][B][G] queue-invariant pipeline, 1 barrier/step ----------
__global__ __launch_bounds__(256, 2) void k_main(const float* __restrict__ w,
                                                 const float* __restrict__ pl,
                                                 const u16* __restrict__ Bpack,
                                                 const float* __restrict__ cp,
                                                 float* __restrict__ out) {
    __shared__ u16 Abuf[2][64 * 64];     // 2 x 8 KB bf16, row = 128 B, XOR-swizzled
    __shared__ float rowsum_s[4][64];
    __shared__ float red[4];

    const int bid = blockIdx.x;
    const int slab = bid & 7;            // XCD-pinned Bpack slice (512 KB, L2-resident)
    const int m0 = (bid >> 3) * 64;
    const int tid = threadIdx.x;
    const int lane = tid & 63, wv = tid >> 6;
    const int l31 = lane & 31, half = lane >> 5;
    const int g4 = lane >> 4, c16 = lane & 15;
    const int kb2base = slab * 64;
    const int swz = (l31 & 7) << 4;

    // staging: wave wv owns rows wv*16..+15; per GLOAD instr j: rows wv*16+4j+g4, 16B at col c16*4
    const float* wthr = w + (size_t)(m0 + wv * 16 + g4) * B_DIM + (size_t)slab * SLABW + c16 * 4;

    int wb[4];
#pragma unroll
    for (int j = 0; j < 4; j++) {
        const int row = wv * 16 + j * 4 + g4;
        wb[j] = row * 128 + ((c16 * 8) ^ ((row & 7) << 4));
    }

    float rcp_cp[2];
#pragma unroll
    for (int n2 = 0; n2 < 2; n2++)
        rcp_cp[n2] = 1.0f / cp[wv * 64 + n2 * 32 + l31];

    f32x16 acc[4];   // [mf*2+n2]: rows mf*32+.., cols wv*64+n2*32+l31
#pragma unroll
    for (int i = 0; i < 4; i++)
#pragma unroll
        for (int r = 0; r < 16; r++) acc[i][r] = 0.f;

    f32x4 Ga[4], Gb[4];
    bf16x8 BX[8], BY[8];

#define SB0 __builtin_amdgcn_sched_barrier(0)
#define WAITV(n) do { asm volatile("s_waitcnt vmcnt(" #n ")" ::: "memory"); SB0; } while (0)
#define LGKM0BAR do { asm volatile("s_waitcnt lgkmcnt(0)" ::: "memory"); \
                      __builtin_amdgcn_s_barrier(); SB0; } while (0)

#define GLOAD(GS, ks) do {                                                               \
        _Pragma("unroll")                                                                \
        for (int j_ = 0; j_ < 4; j_++)                                                   \
            GS[j_] = *(const f32x4*)(wthr + (size_t)(4 * j_) * B_DIM + (size_t)(ks) * 64); \
        SB0;                                                                             \
    } while (0)

#define LOADB(BS, s_) do {                                                               \
        _Pragma("unroll")                                                                \
        for (int kf_ = 0; kf_ < 4; kf_++)                                                \
            _Pragma("unroll")                                                            \
            for (int n2_ = 0; n2_ < 2; n2_++)                                            \
                BS[kf_ * 2 + n2_] = *(const bf16x8*)(Bpack +                             \
                    ((size_t)((kb2base + (s_) * 4 + kf_) * 8 + wv * 2 + n2_)) * 512 + lane * 8); \
        SB0;                                                                             \
    } while (0)

#define PERM2(hi, lo) __builtin_amdgcn_perm(__float_as_uint(hi), __float_as_uint(lo), 0x07060302u)

#define CONV(GS, bufi) do {                                                              \
        char* lb_ = (char*)&Abuf[(bufi)][0];                                             \
        _Pragma("unroll")                                                                \
        for (int j_ = 0; j_ < 4; j_++) {                                                 \
            uint2 p_;                                                                    \
            p_.x = PERM2(GS[j_][1], GS[j_][0]);                                          \
            p_.y = PERM2(GS[j_][3], GS[j_][2]);                                          \
            *(uint2*)(lb_ + wb[j_]) = p_;                                                \
        }                                                                                \
    } while (0)

#define COMP(bufi, BS) do {                                                              \
        const char* ab_ = (const char*)&Abuf[(bufi)][0];                                 \
        _Pragma("unroll")                                                                \
        for (int kf_ = 0; kf_ < 4; kf_++) {                                              \
            const int ko_ = (kf_ * 32 + half * 16) ^ swz;                                \
            bf16x8 a0_ = *(const bf16x8*)(ab_ + l31 * 128 + ko_);                        \
            bf16x8 a1_ = *(const bf16x8*)(ab_ + (32 + l31) * 128 + ko_);                 \
            acc[0] = __builtin_amdgcn_mfma_f32_32x32x16_bf16(a0_, BS[kf_ * 2 + 0], acc[0], 0, 0, 0); \
            acc[1] = __builtin_amdgcn_mfma_f32_32x32x16_bf16(a0_, BS[kf_ * 2 + 1], acc[1], 0, 0, 0); \
            acc[2] = __builtin_amdgcn_mfma_f32_32x32x16_bf16(a1_, BS[kf_ * 2 + 0], acc[2], 0, 0, 0); \
            acc[3] = __builtin_amdgcn_mfma_f32_32x32x16_bf16(a1_, BS[kf_ * 2 + 1], acc[3], 0, 0, 0); \
        }                                                                                \
        SB0;                                                                             \
    } while (0)

// entry invariant at step s: queue = [G(s+1):4][B(s+1):8][G(s+2):4]
#define BODY(s_, GS, BS, WG, WB, DOG, DOB) do {                                          \
        WAITV(WG);                       /* G(s+1) landed, cover ~2 steps */             \
        CONV(GS, ((s_) + 1) & 1);                                                        \
        WAITV(WB);                       /* B(s+1) landed; G(s+2) stays in flight */     \
        COMP((s_) & 1, BS);                                                              \
        if (DOB) LOADB(BS, (s_) + 2);    /* into set just consumed */                    \
        if (DOG) GLOAD(GS, (s_) + 3);    /* into set just converted */                   \
        LGKM0BAR;                                                                        \
    } while (0)

    // prologue -> establish invariant for s=0: [G1:4][B1:8][G2:4]
    LOADB(BX, 0);
    GLOAD(Ga, 0);
    GLOAD(Gb, 1);
    WAITV(4);          // B0 + G0 landed
    CONV(Ga, 0);
    LOADB(BY, 1);
    GLOAD(Ga, 2);
    LGKM0BAR;

    for (int s = 0; s < NKS - 4; s += 2) {   // s = 0,2,..,10
        BODY(s,     Gb, BX, 12, 4, 1, 1);
        BODY(s + 1, Ga, BY, 12, 4, 1, 1);
    }
    BODY(12, Gb, BX, 12, 4, 1, 1);   // GLOAD(15), LOADB(14)
    BODY(13, Ga, BY, 12, 4, 0, 1);   // LOADB(15)
    BODY(14, Gb, BX,  8, 0, 0, 0);
    COMP(1, BY);                     // s = 15

#undef BODY
#undef COMP
#undef CONV
#undef PERM2
#undef LOADB
#undef GLOAD

    // row sums fall out of acc: sum_c Q[r,c] = rowW_slab[r] (softmax rows of p_r sum to 1)
#pragma unroll
    for (int mf = 0; mf < 2; mf++) {
#pragma unroll
        for (int reg = 0; reg < 16; reg++) {
            float v = acc[mf * 2 + 0][reg] + acc[mf * 2 + 1][reg];
            v += __shfl_xor(v, 1, 64);
            v += __shfl_xor(v, 2, 64);
            v += __shfl_xor(v, 4, 64);
            v += __shfl_xor(v, 8, 64);
            v += __shfl_xor(v, 16, 64);
            const int lrow = mf * 32 + (reg & 3) + 8 * (reg >> 2) + 4 * half;
            if (l31 == 0) rowsum_s[wv][lrow] = v;
        }
    }
    __syncthreads();

    // epilogue: tot = sum over (row,col) of [q + p*(rs - 2q)] / cp
    float tot = 0.f;
#pragma unroll
    for (int mf = 0; mf < 2; mf++) {
#pragma unroll
        for (int reg = 0; reg < 16; reg++) {
            const int lrow = mf * 32 + (reg & 3) + 8 * (reg >> 2) + 4 * half;
            const float rs = rowsum_s[0][lrow] + rowsum_s[1][lrow]
                           + rowsum_s[2][lrow] + rowsum_s[3][lrow];
            const float* plrow = pl + (size_t)(m0 + lrow) * K_CL + wv * 64 + l31;
#pragma unroll
            for (int n2 = 0; n2 < 2; n2++) {
                const float q = acc[mf * 2 + n2][reg];
                const float p = plrow[n2 * 32];
                tot += (q + p * (rs - 2.0f * q)) * rcp_cp[n2];
            }
        }
    }
    for (int o = 32; o; o >>= 1) tot += __shfl_down(tot, o, 64);
    if (lane == 0) red[wv] = tot;
    __syncthreads();
    if (tid == 0) atomicAdd(out, red[0] + red[1] + red[2] + red[3]);

#undef WAITV
#undef LGKM0BAR
#undef SB0
}

extern "C" void kernel_launch(void* const* d_in, const int* in_sizes, int n_in,
                              void* d_out, int out_size, void* d_ws, size_t ws_size,
                              hipStream_t stream) {
    const float* w  = (const float*)d_in[0];
    const float* pl = (const float*)d_in[1];
    const float* pr = (const float*)d_in[2];
    const float* cp = (const float*)d_in[3];
    float* out = (float*)d_out;

    u16* Bpack = (u16*)d_ws;   // 4 MB

    k_prep<<<dim3(512), dim3(256), 0, stream>>>(pr, Bpack, out);
    k_main<<<dim3(128 * NSLAB), dim3(256), 0, stream>>>(w, pl, Bpack, cp, out);
}